// Round 1
// baseline (754.054 us; speedup 1.0000x reference)
//
#include <hip/hip_runtime.h>

#define BS  16
#define TT  50
#define NN  100
#define OBSF 40
#define ACTF 8
#define HIDF 64
#define LATF 16

__device__ __forceinline__ float sigmf(float x) { return 1.f / (1.f + __expf(-x)); }
__device__ __forceinline__ float tanh_fast(float x) { return 1.f - 2.f / (__expf(2.f * x) + 1.f); }

// ---------------------------------------------------------------- adj bitmask
__global__ void adjmask_kernel(const int* __restrict__ adj, unsigned long long* __restrict__ mask) {
    int n = threadIdx.x;
    if (n < NN) {
        unsigned long long w0 = 0ull, w1 = 0ull;
        for (int m = 0; m < 64; ++m)  if (adj[n * NN + m] > 0) w0 |= (1ull << m);
        for (int m = 64; m < NN; ++m) if (adj[n * NN + m] > 0) w1 |= (1ull << (m - 64));
        mask[2 * n] = w0; mask[2 * n + 1] = w1;
    }
}

// ---------------------------------------------------------------- embedding
// emb[b][t][n][j] = o@W_obs + a_prev@W_pa + m@W_mk + biases + id_emb[n]
__global__ void emb_kernel(const float* __restrict__ o, const float* __restrict__ ap,
                           const float* __restrict__ mk,
                           const float* __restrict__ Wobs, const float* __restrict__ bobs,
                           const float* __restrict__ Wpa, const float* __restrict__ bpa,
                           const float* __restrict__ Wmk, const float* __restrict__ bmk,
                           const float* __restrict__ idemb, float* __restrict__ emb) {
    int g = blockIdx.x;               // (b*T+t)*N + n
    int n = g % NN;
    int j = threadIdx.x;              // 0..63
    __shared__ float so[OBSF], sa[ACTF], sm[ACTF];
    if (j < OBSF) so[j] = o[(size_t)g * OBSF + j];
    if (j >= 40 && j < 48) sa[j - 40] = ap[(size_t)g * ACTF + (j - 40)];
    if (j >= 48 && j < 56) sm[j - 48] = mk[(size_t)g * ACTF + (j - 48)];
    __syncthreads();
    float acc = bobs[j] + bpa[j] + bmk[j] + idemb[n * HIDF + j];
    #pragma unroll
    for (int k = 0; k < OBSF; ++k) acc += so[k] * Wobs[k * HIDF + j];
    #pragma unroll
    for (int k = 0; k < ACTF; ++k) acc += sa[k] * Wpa[k * HIDF + j] + sm[k] * Wmk[k * HIDF + j];
    emb[(size_t)g * HIDF + j] = acc;
}

// ---------------------------------------------------------------- xW = x @ Wih + bih + bhh
// layout out: xW[s][t][256], s = b*N + n
__global__ void xw_kernel(const float* __restrict__ emb, const float* __restrict__ Wih,
                          const float* __restrict__ bih, const float* __restrict__ bhh,
                          float* __restrict__ xW) {
    int blk = blockIdx.x;
    int chunk = blk % 5;              // 5 chunks of 10 timesteps
    int s = blk / 5;
    int b = s / NN, n = s % NN;
    int t0 = chunk * 10;
    __shared__ float se[10][HIDF];
    int tid = threadIdx.x;
    for (int i = tid; i < 10 * HIDF; i += 256) {
        int r = i >> 6, k = i & 63;
        se[r][k] = emb[((size_t)(b * TT + t0 + r) * NN + n) * HIDF + k];
    }
    __syncthreads();
    int j = tid;                      // gate col 0..255
    float base = bih[j] + bhh[j];
    float acc[10];
    #pragma unroll
    for (int r = 0; r < 10; ++r) acc[r] = base;
    for (int k = 0; k < HIDF; ++k) {
        float w = Wih[k * 256 + j];
        #pragma unroll
        for (int r = 0; r < 10; ++r) acc[r] += se[r][k] * w;
    }
    #pragma unroll
    for (int r = 0; r < 10; ++r) xW[((size_t)s * TT + t0 + r) * 256 + j] = acc[r];
}

// ---------------------------------------------------------------- LSTM recurrence
// one block per sequence s = b*N+n; thread j owns gate column j; Whh column in regs
__launch_bounds__(256)
__global__ void lstm_kernel(const float* __restrict__ xW, const float* __restrict__ Whh,
                            float* __restrict__ xenc) {
    int s = blockIdx.x;
    int b = s / NN, n = s % NN;
    int j = threadIdx.x;
    __shared__ __align__(16) float hs[HIDF];
    __shared__ float gs[256];
    float wcol[HIDF];
    #pragma unroll
    for (int k = 0; k < HIDF; ++k) wcol[k] = Whh[k * 256 + j];
    if (j < HIDF) hs[j] = 0.f;
    float c = 0.f;                    // used by j < 64 only
    __syncthreads();
    for (int t = 0; t < TT; ++t) {
        float acc = xW[((size_t)s * TT + t) * 256 + j];
        const float4* h4 = (const float4*)hs;
        #pragma unroll
        for (int k4 = 0; k4 < HIDF / 4; ++k4) {
            float4 hv = h4[k4];
            acc += hv.x * wcol[4 * k4] + hv.y * wcol[4 * k4 + 1]
                 + hv.z * wcol[4 * k4 + 2] + hv.w * wcol[4 * k4 + 3];
        }
        gs[j] = acc;
        __syncthreads();
        if (j < HIDF) {
            float ig = sigmf(gs[j]);
            float fg = sigmf(gs[64 + j]);
            float gg = tanh_fast(gs[128 + j]);
            float og = sigmf(gs[192 + j]);
            c = fg * c + ig * gg;
            float h = og * tanh_fast(c);
            hs[j] = h;
            xenc[((size_t)(b * TT + t) * NN + n) * HIDF + j] = h;
        }
        __syncthreads();
    }
}

// ---------------------------------------------------------------- fused GAT layer
// OUTMODE 0: concat heads + elu(+bias) ; 1: single head + bias ; 2: single head + bias, * mgate
template <int FIN1, int FIN2, int H, int FOUT, int OUTMODE>
__launch_bounds__(256)
__global__ void gat_kernel(const float* __restrict__ x1, const float* __restrict__ x2,
                           const float* __restrict__ w, const float* __restrict__ asrc,
                           const float* __restrict__ adst, const float* __restrict__ bias,
                           const unsigned long long* __restrict__ adjmask,
                           const float* __restrict__ mgate, float* __restrict__ out) {
    constexpr int FIN = FIN1 + FIN2;
    constexpr int HF = H * FOUT;
    __shared__ __align__(16) float sx[NN * FIN];
    __shared__ __align__(16) float sh[NN * HF];
    __shared__ float ses[H * NN];
    __shared__ float sed[H * NN];
    __shared__ unsigned long long smask[2 * NN];
    int g = blockIdx.x;
    int tid = threadIdx.x;

    for (int i = tid; i < NN * FIN1; i += 256) {
        int n = i / FIN1, k = i % FIN1;
        sx[n * FIN + k] = x1[((size_t)g * NN + n) * FIN1 + k];
    }
    if constexpr (FIN2 > 0) {
        for (int i = tid; i < NN * FIN2; i += 256) {
            int n = i / FIN2, k = i % FIN2;
            sx[n * FIN + FIN1 + k] = x2[(size_t)g * FIN2 + k];
        }
    }
    if (tid < 2 * NN) smask[tid] = adjmask[tid];
    __syncthreads();

    // phase 1: h = x @ w  (+ fused e_src/e_dst via shfl reduction over FOUT lanes)
    {
        const int ho = tid % HF;              // constant per thread (256 % HF == 0)
        const int h = ho / FOUT, o = ho % FOUT;
        float wcol[FIN];
        #pragma unroll
        for (int k = 0; k < FIN; ++k) wcol[k] = w[(h * FIN + k) * FOUT + o];
        const float as = asrc[ho], ad = adst[ho];
        for (int n = tid / HF; n < NN; n += 256 / HF) {
            float acc = 0.f;
            #pragma unroll
            for (int k = 0; k < FIN; ++k) acc += sx[n * FIN + k] * wcol[k];
            sh[n * HF + ho] = acc;
            float vs = acc * as, vd = acc * ad;
            #pragma unroll
            for (int off = FOUT / 2; off >= 1; off >>= 1) {
                vs += __shfl_xor(vs, off, 64);
                vd += __shfl_xor(vd, off, 64);
            }
            if (o == 0) { ses[h * NN + n] = vs; sed[h * NN + n] = vd; }
        }
    }
    __syncthreads();

    // phase 2: masked softmax over m + aggregation
    for (int idx = tid; idx < H * NN; idx += 256) {
        int h = idx / NN, n = idx % NN;
        unsigned long long m0 = smask[2 * n], m1 = smask[2 * n + 1];
        float esn = ses[h * NN + n];
        float maxv = -3.0e38f;
        for (int m = 0; m < NN; ++m) {
            bool valid = (m < 64) ? ((m0 >> m) & 1ull) : ((m1 >> (m - 64)) & 1ull);
            if (valid) {
                float e = esn + sed[h * NN + m];
                e = (e > 0.f) ? e : 0.2f * e;
                maxv = fmaxf(maxv, e);
            }
        }
        float denom = 0.f;
        float acc[FOUT];
        #pragma unroll
        for (int o = 0; o < FOUT; ++o) acc[o] = 0.f;
        for (int m = 0; m < NN; ++m) {
            bool valid = (m < 64) ? ((m0 >> m) & 1ull) : ((m1 >> (m - 64)) & 1ull);
            if (valid) {
                float e = esn + sed[h * NN + m];
                e = (e > 0.f) ? e : 0.2f * e;
                float p = __expf(e - maxv);
                denom += p;
                const float* hrow = &sh[m * HF + h * FOUT];
                #pragma unroll
                for (int o = 0; o < FOUT; ++o) acc[o] += p * hrow[o];
            }
        }
        float inv = 1.f / denom;
        if constexpr (OUTMODE == 0) {
            #pragma unroll
            for (int o = 0; o < FOUT; ++o) {
                float v = acc[o] * inv + bias[h * FOUT + o];
                v = (v > 0.f) ? v : (__expf(v) - 1.f);          // elu
                out[((size_t)g * NN + n) * HF + h * FOUT + o] = v;
            }
        } else if constexpr (OUTMODE == 1) {
            #pragma unroll
            for (int o = 0; o < FOUT; ++o)
                out[((size_t)g * NN + n) * FOUT + o] = acc[o] * inv + bias[o];
        } else {
            #pragma unroll
            for (int o = 0; o < FOUT; ++o) {
                size_t oi = ((size_t)g * NN + n) * FOUT + o;
                out[oi] = (acc[o] * inv + bias[o]) * mgate[oi];
            }
        }
    }
}

// ---------------------------------------------------------------- pool + reparameterize
__global__ void pool_kernel(const float* __restrict__ g2, const float* __restrict__ eps,
                            float* __restrict__ z, float* __restrict__ dout) {
    int g = blockIdx.x;
    int c = threadIdx.x;
    __shared__ float s[2 * LATF];
    if (c < 2 * LATF) {
        float sum = 0.f;
        for (int n = 0; n < NN; ++n) sum += g2[((size_t)g * NN + n) * (2 * LATF) + c];
        s[c] = sum * (1.f / NN);
    }
    __syncthreads();
    if (c < LATF) {
        float mu = s[c], lv = s[LATF + c];
        dout[640000 + (size_t)g * LATF + c] = mu;
        dout[652800 + (size_t)g * LATF + c] = lv;
        z[(size_t)g * LATF + c] = mu + eps[(size_t)g * LATF + c] * __expf(0.5f * lv);
    }
}

// ---------------------------------------------------------------- launch
extern "C" void kernel_launch(void* const* d_in, const int* in_sizes, int n_in,
                              void* d_out, int out_size, void* d_ws, size_t ws_size,
                              hipStream_t stream) {
    const float* o     = (const float*)d_in[0];
    const float* aprev = (const float*)d_in[1];
    const float* mk    = (const float*)d_in[2];
    const float* eps   = (const float*)d_in[3];
    const int*   adj   = (const int*)d_in[4];
    const float* Wobs  = (const float*)d_in[5];
    const float* bobs  = (const float*)d_in[6];
    const float* Wpa   = (const float*)d_in[7];
    const float* bpa   = (const float*)d_in[8];
    const float* Wmk   = (const float*)d_in[9];
    const float* bmk   = (const float*)d_in[10];
    const float* idemb = (const float*)d_in[11];
    const float* lWih  = (const float*)d_in[12];
    const float* lWhh  = (const float*)d_in[13];
    const float* lbih  = (const float*)d_in[14];
    const float* lbhh  = (const float*)d_in[15];
    const float* e1w = (const float*)d_in[16]; const float* e1s = (const float*)d_in[17];
    const float* e1d = (const float*)d_in[18]; const float* e1b = (const float*)d_in[19];
    const float* e2w = (const float*)d_in[20]; const float* e2s = (const float*)d_in[21];
    const float* e2d = (const float*)d_in[22]; const float* e2b = (const float*)d_in[23];
    const float* d1w = (const float*)d_in[24]; const float* d1s = (const float*)d_in[25];
    const float* d1d = (const float*)d_in[26]; const float* d1b = (const float*)d_in[27];
    const float* d2w = (const float*)d_in[28]; const float* d2s = (const float*)d_in[29];
    const float* d2d = (const float*)d_in[30]; const float* d2b = (const float*)d_in[31];
    const float* d3w = (const float*)d_in[32]; const float* d3s = (const float*)d_in[33];
    const float* d3d = (const float*)d_in[34]; const float* d3b = (const float*)d_in[35];

    float* ws   = (float*)d_ws;
    float* emb  = ws;                  // [0, 5.12M)
    float* xenc = ws + 5120000;        // [5.12M, 10.24M)
    float* xW   = ws + 10240000;       // [10.24M, 30.72M)  dead after lstm
    float* g1o  = ws + 10240000;       // [10.24M, 15.36M)  reuse of xW region
    float* g2o  = ws + 15360000;       // [15.36M, 17.92M)
    float* z    = ws + 17920000;       // [17.92M, 17.933M)
    float* d1o  = ws + 18000000;       // [18.0M, 23.12M)
    float* d2o  = ws + 23200000;       // [23.2M, 28.32M)
    unsigned long long* amask = (unsigned long long*)(ws + 30720000);
    float* out = (float*)d_out;

    adjmask_kernel<<<1, 128, 0, stream>>>(adj, amask);
    emb_kernel<<<BS * TT * NN, 64, 0, stream>>>(o, aprev, mk, Wobs, bobs, Wpa, bpa,
                                                Wmk, bmk, idemb, emb);
    xw_kernel<<<1600 * 5, 256, 0, stream>>>(emb, lWih, lbih, lbhh, xW);
    lstm_kernel<<<1600, 256, 0, stream>>>(xW, lWhh, xenc);
    gat_kernel<64, 0, 4, 16, 0><<<800, 256, 0, stream>>>(xenc, nullptr, e1w, e1s, e1d, e1b,
                                                         amask, nullptr, g1o);
    gat_kernel<64, 0, 1, 32, 1><<<800, 256, 0, stream>>>(g1o, nullptr, e2w, e2s, e2d, e2b,
                                                         amask, nullptr, g2o);
    pool_kernel<<<800, 64, 0, stream>>>(g2o, eps, z, out);
    gat_kernel<64, 16, 4, 16, 0><<<800, 256, 0, stream>>>(emb, z, d1w, d1s, d1d, d1b,
                                                          amask, nullptr, d1o);
    gat_kernel<64, 0, 4, 16, 0><<<800, 256, 0, stream>>>(d1o, nullptr, d2w, d2s, d2d, d2b,
                                                         amask, nullptr, d2o);
    gat_kernel<64, 0, 1, 8, 2><<<800, 256, 0, stream>>>(d2o, nullptr, d3w, d3s, d3d, d3b,
                                                        amask, mk, out);
}

// Round 2
// 590.777 us; speedup vs baseline: 1.2764x; 1.2764x over previous
//
#include <hip/hip_runtime.h>

#define BS  16
#define TT  50
#define NN  100
#define OBSF 40
#define ACTF 8
#define HIDF 64
#define LATF 16

__device__ __forceinline__ float sigmf(float x) { return 1.f / (1.f + __expf(-x)); }
__device__ __forceinline__ float tanh_fast(float x) { return 1.f - 2.f / (__expf(2.f * x) + 1.f); }

// ---------------------------------------------------------------- adj bitmask
__global__ void adjmask_kernel(const int* __restrict__ adj, unsigned long long* __restrict__ mask) {
    int n = threadIdx.x;
    if (n < NN) {
        unsigned long long w0 = 0ull, w1 = 0ull;
        for (int m = 0; m < 64; ++m)  if (adj[n * NN + m] > 0) w0 |= (1ull << m);
        for (int m = 64; m < NN; ++m) if (adj[n * NN + m] > 0) w1 |= (1ull << (m - 64));
        mask[2 * n] = w0; mask[2 * n + 1] = w1;
    }
}

// ---------------------------------------------------------------- embedding
__global__ void emb_kernel(const float* __restrict__ o, const float* __restrict__ ap,
                           const float* __restrict__ mk,
                           const float* __restrict__ Wobs, const float* __restrict__ bobs,
                           const float* __restrict__ Wpa, const float* __restrict__ bpa,
                           const float* __restrict__ Wmk, const float* __restrict__ bmk,
                           const float* __restrict__ idemb, float* __restrict__ emb) {
    int g = blockIdx.x;               // (b*T+t)*N + n
    int n = g % NN;
    int j = threadIdx.x;              // 0..63
    __shared__ float so[OBSF], sa[ACTF], sm[ACTF];
    if (j < OBSF) so[j] = o[(size_t)g * OBSF + j];
    if (j >= 40 && j < 48) sa[j - 40] = ap[(size_t)g * ACTF + (j - 40)];
    if (j >= 48 && j < 56) sm[j - 48] = mk[(size_t)g * ACTF + (j - 48)];
    __syncthreads();
    float acc = bobs[j] + bpa[j] + bmk[j] + idemb[n * HIDF + j];
    #pragma unroll
    for (int k = 0; k < OBSF; ++k) acc += so[k] * Wobs[k * HIDF + j];
    #pragma unroll
    for (int k = 0; k < ACTF; ++k) acc += sa[k] * Wpa[k * HIDF + j] + sm[k] * Wmk[k * HIDF + j];
    emb[(size_t)g * HIDF + j] = acc;
}

// ---------------------------------------------------------------- xW = x @ Wih + bih + bhh
__global__ void xw_kernel(const float* __restrict__ emb, const float* __restrict__ Wih,
                          const float* __restrict__ bih, const float* __restrict__ bhh,
                          float* __restrict__ xW) {
    int blk = blockIdx.x;
    int chunk = blk % 5;
    int s = blk / 5;
    int b = s / NN, n = s % NN;
    int t0 = chunk * 10;
    __shared__ float se[10][HIDF];
    int tid = threadIdx.x;
    for (int i = tid; i < 10 * HIDF; i += 256) {
        int r = i >> 6, k = i & 63;
        se[r][k] = emb[((size_t)(b * TT + t0 + r) * NN + n) * HIDF + k];
    }
    __syncthreads();
    int j = tid;
    float base = bih[j] + bhh[j];
    float acc[10];
    #pragma unroll
    for (int r = 0; r < 10; ++r) acc[r] = base;
    for (int k = 0; k < HIDF; ++k) {
        float w = Wih[k * 256 + j];
        #pragma unroll
        for (int r = 0; r < 10; ++r) acc[r] += se[r][k] * w;
    }
    #pragma unroll
    for (int r = 0; r < 10; ++r) xW[((size_t)s * TT + t0 + r) * 256 + j] = acc[r];
}

// ---------------------------------------------------------------- LSTM recurrence
__launch_bounds__(256)
__global__ void lstm_kernel(const float* __restrict__ xW, const float* __restrict__ Whh,
                            float* __restrict__ xenc) {
    int s = blockIdx.x;
    int b = s / NN, n = s % NN;
    int j = threadIdx.x;
    __shared__ __align__(16) float hs[HIDF];
    __shared__ float gs[256];
    float wcol[HIDF];
    #pragma unroll
    for (int k = 0; k < HIDF; ++k) wcol[k] = Whh[k * 256 + j];
    if (j < HIDF) hs[j] = 0.f;
    float c = 0.f;
    __syncthreads();
    for (int t = 0; t < TT; ++t) {
        float acc = xW[((size_t)s * TT + t) * 256 + j];
        const float4* h4 = (const float4*)hs;
        #pragma unroll
        for (int k4 = 0; k4 < HIDF / 4; ++k4) {
            float4 hv = h4[k4];
            acc += hv.x * wcol[4 * k4] + hv.y * wcol[4 * k4 + 1]
                 + hv.z * wcol[4 * k4 + 2] + hv.w * wcol[4 * k4 + 3];
        }
        gs[j] = acc;
        __syncthreads();
        if (j < HIDF) {
            float ig = sigmf(gs[j]);
            float fg = sigmf(gs[64 + j]);
            float gg = tanh_fast(gs[128 + j]);
            float og = sigmf(gs[192 + j]);
            c = fg * c + ig * gg;
            float h = og * tanh_fast(c);
            hs[j] = h;
            xenc[((size_t)(b * TT + t) * NN + n) * HIDF + j] = h;
        }
        __syncthreads();
    }
}

// ---------------------------------------------------------------- fused GAT layer
// sh aliases sx (phase-1 result staged in registers). Single-pass softmax (no max),
// branchless mask, float4 LDS/global. SPLIT divides FOUT across threads in phase 2.
// OUTMODE 0: concat heads + elu(+bias); 1: single head + bias; 2: +bias then * mgate
template <int FIN1, int FIN2, int H, int FOUT, int SPLIT, int OUTMODE>
__launch_bounds__(256)
__global__ void gat_kernel(const float* __restrict__ x1, const float* __restrict__ x2,
                           const float* __restrict__ w, const float* __restrict__ asrc,
                           const float* __restrict__ adst, const float* __restrict__ bias,
                           const unsigned long long* __restrict__ adjmask,
                           const float* __restrict__ mgate, float* __restrict__ out) {
    constexpr int FIN = FIN1 + FIN2;
    constexpr int HF = H * FOUT;
    constexpr int NPT = 256 / HF;                    // rows in flight (4 / 8 / 32)
    constexpr int ROWS = (NN + NPT - 1) / NPT;       // 25 / 13 / 4
    constexpr int SB = NN * (FIN > HF ? FIN : HF);
    __shared__ __align__(16) float sbuf[SB];         // sx, later aliased as sh
    __shared__ __align__(16) float ses[H * NN];
    __shared__ __align__(16) float sed[H * NN];
    __shared__ unsigned long long smask[2 * NN];
    int g = blockIdx.x;
    int tid = threadIdx.x;

    for (int i = tid; i < NN * FIN1; i += 256) {
        int n = i / FIN1, k = i % FIN1;
        sbuf[n * FIN + k] = x1[((size_t)g * NN + n) * FIN1 + k];
    }
    if constexpr (FIN2 > 0) {
        for (int i = tid; i < NN * FIN2; i += 256) {
            int n = i / FIN2, k = i % FIN2;
            sbuf[n * FIN + FIN1 + k] = x2[(size_t)g * FIN2 + k];
        }
    }
    if (tid < 2 * NN) smask[tid] = adjmask[tid];
    __syncthreads();

    // ---- phase 1: h = x @ w (register-staged), fused e_src/e_dst shfl reduction
    const int ho = tid % HF;
    const int h = ho / FOUT, o = ho % FOUT;
    const int n0 = tid / HF;
    float racc[ROWS];
    {
        float wcol[FIN];
        #pragma unroll
        for (int k = 0; k < FIN; ++k) wcol[k] = w[(h * FIN + k) * FOUT + o];
        const float as = asrc[ho], ad = adst[ho];
        #pragma unroll
        for (int r = 0; r < ROWS; ++r) {
            int n = n0 + r * NPT;
            float acc = 0.f;
            if (ROWS * NPT == NN || n < NN) {
                const float4* row = (const float4*)&sbuf[n * FIN];
                #pragma unroll
                for (int k4 = 0; k4 < FIN / 4; ++k4) {
                    float4 xv = row[k4];
                    acc += xv.x * wcol[4 * k4] + xv.y * wcol[4 * k4 + 1]
                         + xv.z * wcol[4 * k4 + 2] + xv.w * wcol[4 * k4 + 3];
                }
            }
            racc[r] = acc;
            float vs = acc * as, vd = acc * ad;
            #pragma unroll
            for (int off = FOUT / 2; off >= 1; off >>= 1) {
                vs += __shfl_xor(vs, off, 64);
                vd += __shfl_xor(vd, off, 64);
            }
            if (o == 0 && (ROWS * NPT == NN || n < NN)) {
                ses[h * NN + n] = vs; sed[h * NN + n] = vd;
            }
        }
    }
    __syncthreads();
    #pragma unroll
    for (int r = 0; r < ROWS; ++r) {
        int n = n0 + r * NPT;
        if (ROWS * NPT == NN || n < NN) sbuf[n * HF + ho] = racc[r];
    }
    __syncthreads();

    // ---- phase 2: single-pass masked softmax + aggregation
    constexpr int FT = FOUT / SPLIT;
    constexpr int ITEMS = H * NN * SPLIT;
    for (int idx = tid; idx < ITEMS; idx += 256) {
        int h2 = idx / (NN * SPLIT);
        int rem = idx % (NN * SPLIT);
        int n = rem / SPLIT;
        int os = (rem % SPLIT) * FT;
        unsigned long long m0 = smask[2 * n], m1 = smask[2 * n + 1];
        float esn = ses[h2 * NN + n];
        float denom = 0.f;
        float acc[FT];
        #pragma unroll
        for (int q = 0; q < FT; ++q) acc[q] = 0.f;
        const float4* sed4 = (const float4*)&sed[h2 * NN];
        #pragma unroll 2
        for (int g4 = 0; g4 < NN / 4; ++g4) {
            float4 ev = sed4[g4];
            unsigned int bits = (g4 < 16) ? (unsigned int)(m0 >> (4 * g4))
                                          : (unsigned int)(m1 >> (4 * g4 - 64));
            float e0 = esn + ev.x; e0 = (e0 > 0.f) ? e0 : 0.2f * e0;
            float e1 = esn + ev.y; e1 = (e1 > 0.f) ? e1 : 0.2f * e1;
            float e2 = esn + ev.z; e2 = (e2 > 0.f) ? e2 : 0.2f * e2;
            float e3 = esn + ev.w; e3 = (e3 > 0.f) ? e3 : 0.2f * e3;
            float p0 = (bits & 1u) ? __expf(e0) : 0.f;
            float p1 = (bits & 2u) ? __expf(e1) : 0.f;
            float p2 = (bits & 4u) ? __expf(e2) : 0.f;
            float p3 = (bits & 8u) ? __expf(e3) : 0.f;
            denom += (p0 + p1) + (p2 + p3);
            const float* r0 = &sbuf[(4 * g4 + 0) * HF + h2 * FOUT + os];
            const float* r1 = &sbuf[(4 * g4 + 1) * HF + h2 * FOUT + os];
            const float* r2 = &sbuf[(4 * g4 + 2) * HF + h2 * FOUT + os];
            const float* r3 = &sbuf[(4 * g4 + 3) * HF + h2 * FOUT + os];
            #pragma unroll
            for (int q4 = 0; q4 < FT / 4; ++q4) {
                float4 v0 = ((const float4*)r0)[q4];
                float4 v1 = ((const float4*)r1)[q4];
                float4 v2 = ((const float4*)r2)[q4];
                float4 v3 = ((const float4*)r3)[q4];
                acc[4 * q4 + 0] += p0 * v0.x + p1 * v1.x + p2 * v2.x + p3 * v3.x;
                acc[4 * q4 + 1] += p0 * v0.y + p1 * v1.y + p2 * v2.y + p3 * v3.y;
                acc[4 * q4 + 2] += p0 * v0.z + p1 * v1.z + p2 * v2.z + p3 * v3.z;
                acc[4 * q4 + 3] += p0 * v0.w + p1 * v1.w + p2 * v2.w + p3 * v3.w;
            }
        }
        float inv = 1.f / denom;
        if constexpr (OUTMODE == 0) {
            float4* op = (float4*)&out[((size_t)g * NN + n) * HF + h2 * FOUT + os];
            #pragma unroll
            for (int q4 = 0; q4 < FT / 4; ++q4) {
                float4 v;
                float a0 = acc[4 * q4 + 0] * inv + bias[h2 * FOUT + os + 4 * q4 + 0];
                float a1 = acc[4 * q4 + 1] * inv + bias[h2 * FOUT + os + 4 * q4 + 1];
                float a2 = acc[4 * q4 + 2] * inv + bias[h2 * FOUT + os + 4 * q4 + 2];
                float a3 = acc[4 * q4 + 3] * inv + bias[h2 * FOUT + os + 4 * q4 + 3];
                v.x = (a0 > 0.f) ? a0 : (__expf(a0) - 1.f);
                v.y = (a1 > 0.f) ? a1 : (__expf(a1) - 1.f);
                v.z = (a2 > 0.f) ? a2 : (__expf(a2) - 1.f);
                v.w = (a3 > 0.f) ? a3 : (__expf(a3) - 1.f);
                op[q4] = v;
            }
        } else if constexpr (OUTMODE == 1) {
            float4* op = (float4*)&out[((size_t)g * NN + n) * FOUT + os];
            #pragma unroll
            for (int q4 = 0; q4 < FT / 4; ++q4) {
                float4 v;
                v.x = acc[4 * q4 + 0] * inv + bias[os + 4 * q4 + 0];
                v.y = acc[4 * q4 + 1] * inv + bias[os + 4 * q4 + 1];
                v.z = acc[4 * q4 + 2] * inv + bias[os + 4 * q4 + 2];
                v.w = acc[4 * q4 + 3] * inv + bias[os + 4 * q4 + 3];
                op[q4] = v;
            }
        } else {
            size_t base = ((size_t)g * NN + n) * FOUT + os;
            float4* op = (float4*)&out[base];
            const float4* mp = (const float4*)&mgate[base];
            #pragma unroll
            for (int q4 = 0; q4 < FT / 4; ++q4) {
                float4 mv = mp[q4];
                float4 v;
                v.x = (acc[4 * q4 + 0] * inv + bias[os + 4 * q4 + 0]) * mv.x;
                v.y = (acc[4 * q4 + 1] * inv + bias[os + 4 * q4 + 1]) * mv.y;
                v.z = (acc[4 * q4 + 2] * inv + bias[os + 4 * q4 + 2]) * mv.z;
                v.w = (acc[4 * q4 + 3] * inv + bias[os + 4 * q4 + 3]) * mv.w;
                op[q4] = v;
            }
        }
    }
}

// ---------------------------------------------------------------- pool + reparameterize
__global__ void pool_kernel(const float* __restrict__ g2, const float* __restrict__ eps,
                            float* __restrict__ z, float* __restrict__ dout) {
    int g = blockIdx.x;
    int c = threadIdx.x;
    __shared__ float s[2 * LATF];
    if (c < 2 * LATF) {
        float sum = 0.f;
        for (int n = 0; n < NN; ++n) sum += g2[((size_t)g * NN + n) * (2 * LATF) + c];
        s[c] = sum * (1.f / NN);
    }
    __syncthreads();
    if (c < LATF) {
        float mu = s[c], lv = s[LATF + c];
        dout[640000 + (size_t)g * LATF + c] = mu;
        dout[652800 + (size_t)g * LATF + c] = lv;
        z[(size_t)g * LATF + c] = mu + eps[(size_t)g * LATF + c] * __expf(0.5f * lv);
    }
}

// ---------------------------------------------------------------- launch
extern "C" void kernel_launch(void* const* d_in, const int* in_sizes, int n_in,
                              void* d_out, int out_size, void* d_ws, size_t ws_size,
                              hipStream_t stream) {
    const float* o     = (const float*)d_in[0];
    const float* aprev = (const float*)d_in[1];
    const float* mk    = (const float*)d_in[2];
    const float* eps   = (const float*)d_in[3];
    const int*   adj   = (const int*)d_in[4];
    const float* Wobs  = (const float*)d_in[5];
    const float* bobs  = (const float*)d_in[6];
    const float* Wpa   = (const float*)d_in[7];
    const float* bpa   = (const float*)d_in[8];
    const float* Wmk   = (const float*)d_in[9];
    const float* bmk   = (const float*)d_in[10];
    const float* idemb = (const float*)d_in[11];
    const float* lWih  = (const float*)d_in[12];
    const float* lWhh  = (const float*)d_in[13];
    const float* lbih  = (const float*)d_in[14];
    const float* lbhh  = (const float*)d_in[15];
    const float* e1w = (const float*)d_in[16]; const float* e1s = (const float*)d_in[17];
    const float* e1d = (const float*)d_in[18]; const float* e1b = (const float*)d_in[19];
    const float* e2w = (const float*)d_in[20]; const float* e2s = (const float*)d_in[21];
    const float* e2d = (const float*)d_in[22]; const float* e2b = (const float*)d_in[23];
    const float* d1w = (const float*)d_in[24]; const float* d1s = (const float*)d_in[25];
    const float* d1d = (const float*)d_in[26]; const float* d1b = (const float*)d_in[27];
    const float* d2w = (const float*)d_in[28]; const float* d2s = (const float*)d_in[29];
    const float* d2d = (const float*)d_in[30]; const float* d2b = (const float*)d_in[31];
    const float* d3w = (const float*)d_in[32]; const float* d3s = (const float*)d_in[33];
    const float* d3d = (const float*)d_in[34]; const float* d3b = (const float*)d_in[35];

    float* ws   = (float*)d_ws;
    float* emb  = ws;
    float* xenc = ws + 5120000;
    float* xW   = ws + 10240000;       // dead after lstm
    float* g1o  = ws + 10240000;       // reuse of xW region
    float* g2o  = ws + 15360000;
    float* z    = ws + 17920000;
    float* d1o  = ws + 18000000;
    float* d2o  = ws + 23200000;
    unsigned long long* amask = (unsigned long long*)(ws + 30720000);
    float* out = (float*)d_out;

    adjmask_kernel<<<1, 128, 0, stream>>>(adj, amask);
    emb_kernel<<<BS * TT * NN, 64, 0, stream>>>(o, aprev, mk, Wobs, bobs, Wpa, bpa,
                                                Wmk, bmk, idemb, emb);
    xw_kernel<<<1600 * 5, 256, 0, stream>>>(emb, lWih, lbih, lbhh, xW);
    lstm_kernel<<<1600, 256, 0, stream>>>(xW, lWhh, xenc);
    gat_kernel<64, 0, 4, 16, 1, 0><<<800, 256, 0, stream>>>(xenc, nullptr, e1w, e1s, e1d, e1b,
                                                            amask, nullptr, g1o);
    gat_kernel<64, 0, 1, 32, 4, 1><<<800, 256, 0, stream>>>(g1o, nullptr, e2w, e2s, e2d, e2b,
                                                            amask, nullptr, g2o);
    pool_kernel<<<800, 64, 0, stream>>>(g2o, eps, z, out);
    gat_kernel<64, 16, 4, 16, 1, 0><<<800, 256, 0, stream>>>(emb, z, d1w, d1s, d1d, d1b,
                                                             amask, nullptr, d1o);
    gat_kernel<64, 0, 4, 16, 1, 0><<<800, 256, 0, stream>>>(d1o, nullptr, d2w, d2s, d2d, d2b,
                                                            amask, nullptr, d2o);
    gat_kernel<64, 0, 1, 8, 2, 2><<<800, 256, 0, stream>>>(d2o, nullptr, d3w, d3s, d3d, d3b,
                                                           amask, mk, out);
}